// Round 1
// baseline (190.317 us; speedup 1.0000x reference)
//
#include <hip/hip_runtime.h>
#include <math.h>

#define E_N 50
#define D_N 100
#define H_N 100
#define XSTR 51          // odd stride: gcd(51 mod 32, 32)=1 -> conflict-free strided access
#define NTHR 256
#define GATHER_IT ((E_N * (D_N / 4) + NTHR - 1) / NTHR)   // 5

__device__ __forceinline__ float bf2f(unsigned int s16) {
    return __uint_as_float(s16 << 16);
}

__device__ __forceinline__ unsigned short f2bf(float f) {
    unsigned int u = __float_as_uint(f);
    unsigned int r = (u + 0x7FFFu + ((u >> 16) & 1u)) >> 16;  // round-nearest-even
    return (unsigned short)r;
}

// scalar typed load
template <bool F32>
__device__ __forceinline__ float ldx(const void* p, int i) {
    if (F32) return reinterpret_cast<const float*>(p)[i];
    return bf2f(reinterpret_cast<const unsigned short*>(p)[i]);
}

// 4-element vector load, group index i4 (elements [4*i4, 4*i4+3])
template <bool F32>
__device__ __forceinline__ float4 ld4(const void* p, long long i4) {
    if (F32) return reinterpret_cast<const float4*>(p)[i4];
    uint2 v = reinterpret_cast<const uint2*>(p)[i4];
    float4 f;
    f.x = bf2f(v.x & 0xFFFFu);
    f.y = bf2f(v.x >> 16);
    f.z = bf2f(v.y & 0xFFFFu);
    f.w = bf2f(v.y >> 16);
    return f;
}

// One block per ego-graph. Only node 0's output is needed:
//   s_j   = (u . x_j) * 0.1,  u = Wk * q0,  q0 = Wq^T x0 + bq  (q0.bk cancels)
//   y     = softmax-weighted sum of x_j
//   out_h = bs + bv*[any edge] + y.Wv[:,h] + x0.Ws[:,h]
// xs is stored TRANSPOSED: xs[d*XSTR + j] = x_j[d]  (bank-conflict-free in every phase)
template <bool F32>
__device__ __forceinline__ void graph_core(
    int g, int tid, int mk, const int* idr,
    const void* __restrict__ emb,
    const void* __restrict__ Wq, const void* __restrict__ bq,
    const void* __restrict__ Wk, const void* __restrict__ Wv,
    const void* __restrict__ bv, const void* __restrict__ Ws,
    const void* __restrict__ bs, void* __restrict__ out,
    float* xs, float* q0s, float* us, float* attns, float* ys, float* den_s)
{
    // ---- gather emb rows -> xs transposed; row indices pre-loaded in idr ----
    #pragma unroll
    for (int r = 0; r < GATHER_IT; ++r) {
        int i = tid + NTHR * r;
        if (i < E_N * (D_N / 4)) {
            int j  = i / 25;
            int d4 = i - j * 25;
            float4 v = ld4<F32>(emb, (long long)idr[r] * (D_N / 4) + d4);
            int d0 = d4 * 4;
            xs[(d0 + 0) * XSTR + j] = v.x;
            xs[(d0 + 1) * XSTR + j] = v.y;
            xs[(d0 + 2) * XSTR + j] = v.z;
            xs[(d0 + 3) * XSTR + j] = v.w;
        }
    }
    __syncthreads();

    // ---- q0[h] = bq[h] + sum_d x0[d] * Wq[d,h]  (coalesced across lanes) ----
    if (tid < H_N) {
        float acc = ldx<F32>(bq, tid);
        #pragma unroll 10
        for (int d = 0; d < D_N; ++d)
            acc = fmaf(xs[d * XSTR], ldx<F32>(Wq, d * H_N + tid), acc);
        q0s[tid] = acc;
    }
    __syncthreads();

    // ---- u[d] = sum_h Wk[d,h] * q0[h]  (per-thread contiguous -> vector loads) ----
    if (tid < D_N) {
        float a0 = 0.f, a1 = 0.f, a2 = 0.f, a3 = 0.f;
        const float4* q4 = reinterpret_cast<const float4*>(q0s);
        #pragma unroll 5
        for (int h4 = 0; h4 < H_N / 4; ++h4) {
            float4 w = ld4<F32>(Wk, (long long)tid * (H_N / 4) + h4);
            float4 q = q4[h4];
            a0 = fmaf(w.x, q.x, a0);
            a1 = fmaf(w.y, q.y, a1);
            a2 = fmaf(w.z, q.z, a2);
            a3 = fmaf(w.w, q.w, a3);
        }
        us[tid] = (a0 + a1) + (a2 + a3);
    }
    __syncthreads();

    // ---- wave 0 only: scores + masked softmax via shuffle reduction ----
    if (tid < 64) {
        float s = 0.f;
        if (tid < E_N) {
            #pragma unroll 10
            for (int d = 0; d < D_N; ++d)
                s = fmaf(us[d], xs[d * XSTR + tid], s);
            s *= 0.1f;  // 1/sqrt(H)
        }
        bool live = (tid < E_N) && (mk != 0);
        float m = live ? s : -3.0e38f;
        #pragma unroll
        for (int off = 32; off; off >>= 1)
            m = fmaxf(m, __shfl_xor(m, off));
        float e = live ? __expf(s - m) : 0.f;
        float den = e;
        #pragma unroll
        for (int off = 32; off; off >>= 1)
            den += __shfl_xor(den, off);
        float inv = den > 0.f ? 1.0f / den : 0.f;
        if (tid < E_N) attns[tid] = e * inv;   // pre-normalized
        if (tid == 0)  *den_s = den;
    }
    __syncthreads();

    // ---- y[d] = sum_j attn_j * x_j[d]  (stride-XSTR across lanes: conflict-free) ----
    if (tid < D_N) {
        float acc = 0.f;
        #pragma unroll 10
        for (int j = 0; j < E_N; ++j)
            acc = fmaf(attns[j], xs[tid * XSTR + j], acc);
        ys[tid] = acc;
    }
    __syncthreads();

    // ---- out[h] = bs[h] + bv[h]*[den>0] + y.Wv[:,h] + x0.Ws[:,h] ----
    if (tid < H_N) {
        float sflag = *den_s > 0.f ? 1.f : 0.f;
        float acc = ldx<F32>(bs, tid) + ldx<F32>(bv, tid) * sflag;
        #pragma unroll 8
        for (int d = 0; d < D_N; ++d) {
            acc = fmaf(ys[d],        ldx<F32>(Wv, d * H_N + tid), acc);
            acc = fmaf(xs[d * XSTR], ldx<F32>(Ws, d * H_N + tid), acc);
        }
        size_t o = (size_t)g * H_N + tid;
        if (F32) reinterpret_cast<float*>(out)[o] = acc;
        else     reinterpret_cast<unsigned short*>(out)[o] = f2bf(acc);
    }
}

__global__ __launch_bounds__(NTHR, 7)   // 7 blocks/CU (LDS-limited); cap VGPR so LDS stays the limit
void graph_enc_kernel(const int* __restrict__ nbr,
                      const int* __restrict__ adj,
                      const void* __restrict__ emb,
                      const void* __restrict__ Wq, const void* __restrict__ bq,
                      const void* __restrict__ Wk, const void* __restrict__ Wv,
                      const void* __restrict__ bv, const void* __restrict__ Ws,
                      const void* __restrict__ bs, void* __restrict__ out)
{
    const int g = blockIdx.x;
    const int tid = threadIdx.x;

    __shared__ __align__(16) float xs[D_N * XSTR];   // 20400 B, transposed [d][j]
    __shared__ __align__(16) float q0s[H_N];
    __shared__ __align__(16) float us[D_N];
    __shared__ __align__(16) float attns[E_N];
    __shared__ __align__(16) float ys[D_N];
    __shared__ float den_s;
    __shared__ int   is_f32_s;

    // ---- issue independent loads up-front (overlap with dtype sniff) ----
    // mask[g, i=0, j] = adj[g, j, 0]  (strided; one latency round, off the phase chain)
    int mk = 0;
    if (tid < E_N) mk = adj[(size_t)g * (E_N * E_N) + tid * E_N];

    // row ids for all gather iterations (nbr row is 4 cache lines, L1-hot)
    int idr[GATHER_IT];
    #pragma unroll
    for (int r = 0; r < GATHER_IT; ++r) {
        int i = tid + NTHR * r;
        idr[r] = (i < E_N * (D_N / 4)) ? nbr[g * E_N + i / 25] : 0;
    }

    // ---- dtype detector: even halfwords of emb decode sane iff data is bf16 ----
    if (tid < 64) {
        unsigned short hw = reinterpret_cast<const unsigned short*>(emb)[tid * 2];
        float v = bf2f(hw);
        float a = fabsf(v);
        int sane = (v == 0.f) || (a >= 1e-4f && a <= 8.0f);
        unsigned long long ball = __ballot(sane);
        if (tid == 0) is_f32_s = (__popcll(ball) < 32) ? 1 : 0;
    }
    __syncthreads();

    if (is_f32_s)
        graph_core<true >(g, tid, mk, idr, emb, Wq, bq, Wk, Wv, bv, Ws, bs, out,
                          xs, q0s, us, attns, ys, &den_s);
    else
        graph_core<false>(g, tid, mk, idr, emb, Wq, bq, Wk, Wv, bv, Ws, bs, out,
                          xs, q0s, us, attns, ys, &den_s);
}

extern "C" void kernel_launch(void* const* d_in, const int* in_sizes, int n_in,
                              void* d_out, int out_size, void* d_ws, size_t ws_size,
                              hipStream_t stream) {
    const int* nbr = (const int*)d_in[0];
    const int* adj = (const int*)d_in[1];
    const void* emb = d_in[2];
    const void* Wq  = d_in[3];
    const void* bq  = d_in[4];
    const void* Wk  = d_in[5];   // d_in[6] = bk cancels inside softmax — unused
    const void* Wv  = d_in[7];
    const void* bv  = d_in[8];
    const void* Ws  = d_in[9];
    const void* bs  = d_in[10];

    const int G = in_sizes[0] / E_N;  // B*L = 3200
    graph_enc_kernel<<<G, NTHR, 0, stream>>>(nbr, adj, emb, Wq, bq, Wk,
                                             Wv, bv, Ws, bs, d_out);
}